// Round 1
// baseline (793.188 us; speedup 1.0000x reference)
//
#include <hip/hip_runtime.h>

#define KNBR 32
#define H1 256
#define H2 128
#define NEG 0.01f

__device__ __forceinline__ float lrelu(float v) { return v > 0.0f ? v : v * NEG; }

// Fused: per-node Linear(K,1)+lrelu  ->  partial GEMV against W2 [N,H1]
// One block = one 256-row chunk. 256 threads = 4 waves; each wave owns row
// residue r_off = wave_id, each lane owns 4 consecutive h-columns (float4).
__global__ __launch_bounds__(256)
void k_l1_gemv(const float* __restrict__ mi, const int* __restrict__ idx,
               const float* __restrict__ W1, const float* __restrict__ b1,
               const float* __restrict__ W2, float* __restrict__ y_acc,
               int N)
{
    __shared__ float x_lds[256];
    __shared__ float y_part[4 * H1];

    const int tid  = threadIdx.x;
    const int base = blockIdx.x * 256;
    const int rows = min(256, N - base);

    // ---- phase A: x[base+tid] = lrelu(dot(mi[idx_row], W1_row) + b1) ----
    if (tid < rows) {
        const int row = base + tid;
        const int4*   ip = (const int4*)(idx + (size_t)row * KNBR);
        const float4* wp = (const float4*)(W1 + (size_t)row * KNBR);
        float s = 0.0f;
#pragma unroll
        for (int j = 0; j < KNBR / 4; ++j) {
            const int4   i4 = ip[j];
            const float4 w4 = wp[j];
            s += mi[i4.x] * w4.x + mi[i4.y] * w4.y +
                 mi[i4.z] * w4.z + mi[i4.w] * w4.w;
        }
        x_lds[tid] = lrelu(s + b1[row]);
    }
    __syncthreads();

    // ---- phase B: acc[h] += x[r] * W2[base+r][h], float4 along h ----
    const int r_off = tid >> 6;        // wave id 0..3
    const int h4    = (tid & 63) * 4;  // first of 4 owned columns
    float4 acc = make_float4(0.f, 0.f, 0.f, 0.f);

    if (rows == 256) {
#pragma unroll 8
        for (int r = 0; r < 64; ++r) {
            const int   rr = r * 4 + r_off;
            const float xv = x_lds[rr];
            const float4 w = *(const float4*)(W2 + (size_t)(base + rr) * H1 + h4);
            acc.x += xv * w.x; acc.y += xv * w.y;
            acc.z += xv * w.z; acc.w += xv * w.w;
        }
    } else {
        for (int r = 0; r < 64; ++r) {
            const int rr = r * 4 + r_off;
            if (rr < rows) {
                const float xv = x_lds[rr];
                const float4 w = *(const float4*)(W2 + (size_t)(base + rr) * H1 + h4);
                acc.x += xv * w.x; acc.y += xv * w.y;
                acc.z += xv * w.z; acc.w += xv * w.w;
            }
        }
    }

    // ---- LDS reduce 4 row-groups, then 1 atomicAdd per h per block ----
    *(float4*)(&y_part[r_off * H1 + h4]) = acc;
    __syncthreads();

    const float s = y_part[tid] + y_part[H1 + tid] +
                    y_part[2 * H1 + tid] + y_part[3 * H1 + tid];
    atomicAdd(&y_acc[tid], s);
}

// Tiny tail MLP: y=lrelu(acc+b2) [256] -> z=lrelu(y@W3+b3) [128] -> scalar out
__global__ __launch_bounds__(256)
void k_mlp(const float* __restrict__ y_acc, const float* __restrict__ b2,
           const float* __restrict__ W3, const float* __restrict__ b3,
           const float* __restrict__ W4, const float* __restrict__ b4,
           float* __restrict__ out)
{
    __shared__ float y[H1];
    __shared__ float z[H2];
    const int tid = threadIdx.x;

    y[tid] = lrelu(y_acc[tid] + b2[tid]);
    __syncthreads();

    if (tid < H2) {
        float s = 0.0f;
#pragma unroll 8
        for (int h = 0; h < H1; ++h) s += y[h] * W3[(size_t)h * H2 + tid];
        z[tid] = lrelu(s + b3[tid]);
    }
    __syncthreads();

    if (tid == 0) {
        float s = 0.0f;
#pragma unroll
        for (int h = 0; h < H2; ++h) s += z[h] * W4[h];
        out[0] = lrelu(s + b4[0]);
    }
}

extern "C" void kernel_launch(void* const* d_in, const int* in_sizes, int n_in,
                              void* d_out, int out_size, void* d_ws, size_t ws_size,
                              hipStream_t stream) {
    const float* mi  = (const float*)d_in[0];
    const int*   idx = (const int*)  d_in[1];
    const float* W1  = (const float*)d_in[2];
    const float* b1  = (const float*)d_in[3];
    const float* W2  = (const float*)d_in[4];
    const float* b2  = (const float*)d_in[5];
    const float* W3  = (const float*)d_in[6];
    const float* b3  = (const float*)d_in[7];
    const float* W4  = (const float*)d_in[8];
    const float* b4  = (const float*)d_in[9];
    float* out   = (float*)d_out;
    float* y_acc = (float*)d_ws;   // H1 floats of partial-sum accumulator

    const int N = in_sizes[0];     // model_input is [N,1]

    // ws is re-poisoned to 0xAA before every launch — zero the accumulator.
    hipMemsetAsync(y_acc, 0, H1 * sizeof(float), stream);

    const int nblocks = (N + 255) / 256;
    k_l1_gemv<<<nblocks, 256, 0, stream>>>(mi, idx, W1, b1, W2, y_acc, N);
    k_mlp<<<1, 256, 0, stream>>>(y_acc, b2, W3, b3, W4, b4, out);
}